// Round 4
// baseline (729.678 us; speedup 1.0000x reference)
//
#include <hip/hip_runtime.h>
#include <hip/hip_bf16.h>
#include <stdint.h>

// SpatioConvLayer: out = relu(x + b + einsum('iok,knm,bitm->botn', theta, Lk, x))
// (1) BT[n][k*1024+m] = bf16(Lk[k][n][m]); (2) Y[(b*48+t)*64+o][k*1024+m]
//     = sum_i theta[i,o,k] * x[b,i,t,m] (bf16, MFMA); (3) out = Y @ BT^T with
//     fused bias + residual + relu. Step (3) = 256x256x64, 4 phases/K-tile,
//     ONE raw s_barrier per phase, cross-barrier read-ahead: each region
//     issues ds_reads for the NEXT phase's fragments so the LDS pipe delivers
//     during the current phase's MFMA (raw s_barrier does not drain lgkmcnt).
//     T1 XCD swizzle + T2 LDS XOR swizzle + counted vmcnt (4/6/6) + setprio.

typedef short bs8 __attribute__((ext_vector_type(8)));   // 8 x bf16 fragment
typedef float f32x4 __attribute__((ext_vector_type(4))); // MFMA accumulator

#define NB   16
#define NC   64
#define NT   48
#define NN   1024
#define NKS  3
#define KDIM 3072  // NKS * NN
#define KT   48    // KDIM / 64 K-tiles

// f32 -> bf16 round-to-nearest-even (finite inputs only)
__device__ __forceinline__ short f2bs(float f) {
  uint32_t u = __builtin_bit_cast(uint32_t, f);
  u = (u + 0x7FFFu + ((u >> 16) & 1u)) >> 16;
  return (short)u;
}

__device__ __forceinline__ void gload16(const void* g, void* l) {
  __builtin_amdgcn_global_load_lds(
      (const __attribute__((address_space(1))) void*)g,
      (__attribute__((address_space(3))) void*)l, 16, 0, 0);
}

// ---------------- prep: BT[n][k*NN+m] = bf16(Lk[k][n][m]) -------------------
__global__ __launch_bounds__(256) void k_prep_bt(const float* __restrict__ Lk,
                                                 short* __restrict__ BT) {
  int gid = blockIdx.x * 256 + threadIdx.x;
  int e = gid * 4;
  int k = e >> 20;
  int rem = e & 1048575;
  int n = rem >> 10;
  int m = rem & 1023;
  float4 v = *reinterpret_cast<const float4*>(Lk + e);
  union { short s[4]; uint64_t u; } p;
  p.s[0] = f2bs(v.x); p.s[1] = f2bs(v.y); p.s[2] = f2bs(v.z); p.s[3] = f2bs(v.w);
  *reinterpret_cast<uint64_t*>(BT + (size_t)n * KDIM + k * NN + m) = p.u;
}

// ---------------- step1: Y[btl*64+o][k*NN+m] = sum_i th[i,o,k] x[b,i,t,m] ---
__global__ __launch_bounds__(256) void k_step1(const float* __restrict__ x,
                                               const float* __restrict__ theta,
                                               short* __restrict__ Y, int b0) {
  __shared__ __align__(16) short th[NKS * 64 * 72];  // [k][o][i] padded 64->72
  int tid = threadIdx.x;
  for (int idx = tid; idx < NC * NC * NKS; idx += 256) {
    int i = idx / (NC * NKS);
    int r = idx - i * (NC * NKS);
    int o = r / NKS;
    int k = r - o * NKS;
    th[(k * 64 + o) * 72 + i] = f2bs(theta[idx]);  // theta[i][o][k]
  }
  __syncthreads();

  int bid = blockIdx.x;
  int mt  = bid & 3;
  int btl = bid >> 2;
  int b_l = btl / NT;
  int t   = btl - b_l * NT;
  int b   = b0 + b_l;

  int lane = tid & 63, wave = tid >> 6;
  int l15 = lane & 15, lg = lane >> 4;
  const float* xb = x + (size_t)b * (NC * NT * NN) + (size_t)t * NN;
  int m0 = mt * 256 + wave * 64;
  size_t yrow0 = (size_t)btl * 64;

  for (int ni = 0; ni < 4; ++ni) {
    int mcol = m0 + ni * 16 + l15;
    float xv[16];
#pragma unroll
    for (int j = 0; j < 16; ++j) {
      int i = ((j >> 3) << 5) + lg * 8 + (j & 7);
      xv[j] = xb[(size_t)i * (NT * NN) + mcol];
    }
    f32x4 acc[3][4];
#pragma unroll
    for (int k = 0; k < 3; ++k)
#pragma unroll
      for (int mi = 0; mi < 4; ++mi)
        acc[k][mi] = (f32x4){0.f, 0.f, 0.f, 0.f};

#pragma unroll
    for (int ks = 0; ks < 2; ++ks) {
      bs8 bfrag;
#pragma unroll
      for (int j = 0; j < 8; ++j) bfrag[j] = f2bs(xv[ks * 8 + j]);
#pragma unroll
      for (int mi = 0; mi < 4; ++mi) {
#pragma unroll
        for (int k = 0; k < 3; ++k) {
          const bs8* ap = reinterpret_cast<const bs8*>(
              &th[(k * 64 + mi * 16 + l15) * 72 + ks * 32 + lg * 8]);
          acc[k][mi] = __builtin_amdgcn_mfma_f32_16x16x32_bf16(
              *ap, bfrag, acc[k][mi], 0, 0, 0);
        }
      }
    }
#pragma unroll
    for (int k = 0; k < 3; ++k)
#pragma unroll
      for (int mi = 0; mi < 4; ++mi)
#pragma unroll
        for (int q = 0; q < 4; ++q) {
          int o = mi * 16 + lg * 4 + q;
          Y[(yrow0 + o) * KDIM + k * NN + mcol] = f2bs(acc[k][mi][q]);
        }
  }
}

// ---------------- big GEMM: C = Y @ BT^T, 256^2 read-ahead pipeline ---------
// Phase order (0,0)->(0,1)->(1,1)->(1,0). Region R_k issues ds_reads for
// phase k+1's fragments; MFMA k consumes fragments read in R_{k-1}.
//   R_P0(t): bfq  <- B1(t)   [buf p]    | stage A1(t+1) -> buf p^1
//   R_P1(t): afY  <- A1(t)   [buf p]    | stage B1(t+1) -> buf p^1 | vmcnt(6)
//   R_P2(t): afX  <- A0(t+1) [buf p^1]  | stage A0(t+2) -> buf p   | vmcnt(6)
//   R_P3(t): B0N  <- B0(t+1) [buf p^1]  | stage B0(t+2) -> buf p   | vmcnt(4)
// In-flight (per thread, 2 loads/stage): 4 -> 6 -> 8(-2) -> 8(-2) -> 8(-4)=4.
// Each vmcnt sits BEFORE the next s_barrier => cross-wave data-ready holds.
// Slot overwrites: every stage targets a slot last ds_read >=3 barriers ago.
// Tail (peeled): t=KT-2 uses vmcnt 6/4/0, t=KT-1 stages/reads nothing extra.

__device__ __forceinline__ void stage_half(const short* __restrict__ src,
                                           short* lds, int h, int tid) {
  int wave = tid >> 6;
#pragma unroll
  for (int r = 0; r < 2; ++r) {
    int idx = h * 1024 + r * 512 + tid;
    int row = idx >> 3, c8 = idx & 7;
    int c8s = c8 ^ (row & 7);                     // inverse-swizzled source
    gload16(src + (size_t)row * KDIM + c8s * 8,
            lds + (h * 1024 + r * 512 + wave * 64) * 8);  // wave-uniform base
  }
}

#define VMC(N) asm volatile("s_waitcnt vmcnt(" #N ")" ::: "memory")
#define BARR()                                 \
  __builtin_amdgcn_s_barrier();                \
  __builtin_amdgcn_sched_barrier(0);

#define READ_A(DST, QM, P)                                                \
  _Pragma("unroll") for (int e = 0; e < 4; ++e)                           \
    _Pragma("unroll") for (int ks = 0; ks < 2; ++ks) {                    \
      int rw = (8 * (QM) + 2 * e + wr) * 16 + l15;                        \
      DST[e][ks] = *(const bs8*)&AL[(P) * 16384 + rw * 64 +               \
                    ((ks * 32 + lg * 8) ^ ((rw & 7) << 3))];              \
    }

#define READ_B(DST, QN, P)                                                \
  _Pragma("unroll") for (int f = 0; f < 2; ++f)                           \
    _Pragma("unroll") for (int ks = 0; ks < 2; ++ks) {                    \
      int rw = (8 * (QN) + 4 * f + wc) * 16 + l15;                        \
      DST[f][ks] = *(const bs8*)&BL[(P) * 16384 + rw * 64 +               \
                    ((ks * 32 + lg * 8) ^ ((rw & 7) << 3))];              \
    }

// ks-outer: dependent MFMAs on the same acc are 8 apart
#define COMPUTE(QM, AF, BF, QN)                                             \
  __builtin_amdgcn_s_setprio(1);                                            \
  _Pragma("unroll") for (int ks = 0; ks < 2; ++ks)                          \
    _Pragma("unroll") for (int e = 0; e < 4; ++e)                           \
      _Pragma("unroll") for (int f = 0; f < 2; ++f)                         \
        acc[4 * (QM) + e][2 * (QN) + f] =                                   \
            __builtin_amdgcn_mfma_f32_16x16x32_bf16(                        \
                AF[e][ks], BF[f][ks], acc[4 * (QM) + e][2 * (QN) + f],      \
                0, 0, 0);                                                   \
  __builtin_amdgcn_s_setprio(0);

// S1: stage t+1 halves exist; S2: stage t+2 halves exist; V1/V2/V3: vmcnts.
#define TILE(t, P, B0C, B0N, S1, S2, V1, V2, V3)                            \
  {                                                                         \
    READ_B(bfq, 1, P);                                                      \
    if (S1) stage_half(Yb + ((t) + 1) * 64, AL + ((P) ^ 1) * 16384, 1, tid);\
    BARR();                                                                 \
    COMPUTE(0, afX, B0C, 0);                                                \
    READ_A(afY, 1, P);                                                      \
    if (S1) stage_half(BTb + ((t) + 1) * 64, BL + ((P) ^ 1) * 16384, 1, tid);\
    V1;                                                                     \
    BARR();                                                                 \
    COMPUTE(0, afX, bfq, 1);                                                \
    if (S1) READ_A(afX, 0, (P) ^ 1);                                        \
    if (S2) stage_half(Yb + ((t) + 2) * 64, AL + (P) * 16384, 0, tid);      \
    V2;                                                                     \
    BARR();                                                                 \
    COMPUTE(1, afY, bfq, 1);                                                \
    if (S1) READ_B(B0N, 0, (P) ^ 1);                                        \
    if (S2) stage_half(BTb + ((t) + 2) * 64, BL + (P) * 16384, 0, tid);     \
    V3;                                                                     \
    BARR();                                                                 \
    COMPUTE(1, afY, B0C, 0);                                                \
  }

__global__ __launch_bounds__(512, 2) void k_gemm(const short* __restrict__ Y,
                                                 const short* __restrict__ BT,
                                                 const float* __restrict__ x,
                                                 const float* __restrict__ bias,
                                                 float* __restrict__ out,
                                                 int b0, int nwg) {
  __shared__ __align__(16) short AL[2 * 16384];  // [buf][256][64] 64 KiB
  __shared__ __align__(16) short BL[2 * 16384];  // [buf][256][64] 64 KiB

  int bid = blockIdx.x;
  int cpx = nwg >> 3;                        // nwg % 8 == 0 -> bijective
  int swz = (bid & 7) * cpx + (bid >> 3);    // XCD-aware swizzle
  int colb = swz & 3;                        // 4 col-blocks (N=1024/256)
  int rowb = swz >> 2;

  int tid = threadIdx.x;
  int lane = tid & 63, wave = tid >> 6;
  int wr = wave >> 2, wc = wave & 3;         // 2M x 4N waves
  int l15 = lane & 15, lg = lane >> 4;
  int row0 = rowb * 256, col0 = colb * 256;

  const short* Yb  = Y  + (size_t)row0 * KDIM;
  const short* BTb = BT + (size_t)col0 * KDIM;

  f32x4 acc[8][4];
#pragma unroll
  for (int j = 0; j < 8; ++j)
#pragma unroll
    for (int i = 0; i < 4; ++i) acc[j][i] = (f32x4){0.f, 0.f, 0.f, 0.f};

  bs8 afX[4][2], afY[4][2], bfq[2][2], bf0a[2][2], bf0b[2][2];

  // prologue: tile0 (A0,A1,B0,B1) -> buf0; A0(1),B0(1) -> buf1 (12 loads)
  stage_half(Yb,        AL,         0, tid);
  stage_half(Yb,        AL,         1, tid);
  stage_half(BTb,       BL,         0, tid);
  stage_half(BTb,       BL,         1, tid);
  stage_half(Yb + 64,   AL + 16384, 0, tid);
  stage_half(BTb + 64,  BL + 16384, 0, tid);
  VMC(4);                                    // tile0 halves landed
  BARR();
  READ_A(afX, 0, 0);                         // A0(0) fragments
  READ_B(bf0a, 0, 0);                        // B0(0) fragments

  for (int t = 0; t < KT - 2; t += 2) {
    TILE(t,     0, bf0a, bf0b, 1, 1, VMC(6), VMC(6), VMC(4));
    TILE(t + 1, 1, bf0b, bf0a, 1, 1, VMC(6), VMC(6), VMC(4));
  }
  TILE(KT - 2, 0, bf0a, bf0b, 1, 0, VMC(6), VMC(4), VMC(0));
  TILE(KT - 1, 1, bf0b, bf0a, 0, 0, (void)0, (void)0, (void)0);

  // epilogue: out = relu(acc + bias[o] + x); abs M-frag 2j+wr, N-frag 4i+wc
#pragma unroll
  for (int j = 0; j < 8; ++j) {
#pragma unroll
    for (int q = 0; q < 4; ++q) {
      int r = row0 + (2 * j + wr) * 16 + lg * 4 + q;  // chunk-local row
      int o = r & 63;
      int btl = r >> 6;
      int tt = btl % NT;
      int bb = b0 + btl / NT;
      float bo = bias[o];
      size_t obase = ((size_t)(bb * 64 + o) * NT + tt) * NN;
#pragma unroll
      for (int i = 0; i < 4; ++i) {
        int n = col0 + (4 * i + wc) * 16 + l15;
        size_t oidx = obase + n;
        float v = acc[j][i][q] + bo + x[oidx];
        out[oidx] = v > 0.f ? v : 0.f;
      }
    }
  }
}

extern "C" void kernel_launch(void* const* d_in, const int* in_sizes, int n_in,
                              void* d_out, int out_size, void* d_ws, size_t ws_size,
                              hipStream_t stream) {
  const float* x     = (const float*)d_in[0];
  const float* Lk    = (const float*)d_in[1];
  const float* theta = (const float*)d_in[2];
  const float* bias  = (const float*)d_in[3];
  float* out = (float*)d_out;

  char* ws = (char*)d_ws;
  short* BT = (short*)ws;                         // 6.29 MB
  short* Y  = (short*)(ws + (size_t)(8u << 20));  // up to 302 MB
  size_t avail = ws_size > ((size_t)8u << 20) ? ws_size - ((size_t)8u << 20) : 0;
  size_t perB = (size_t)NT * NC * KDIM * 2;       // 18,874,368 B per batch-row
  int bc = 16;
  while (bc > 1 && (size_t)bc * perB > avail) bc >>= 1;  // chunk over b if needed

  k_prep_bt<<<dim3(3072), dim3(256), 0, stream>>>(Lk, BT);
  for (int b0 = 0; b0 < NB; b0 += bc) {
    k_step1<<<dim3(bc * 192), dim3(256), 0, stream>>>(x, theta, Y, b0);
    int nwg = bc * 48;  // (bc*3072/256 rowb) * 4 colb, divisible by 8
    k_gemm<<<dim3(nwg), dim3(512), 0, stream>>>(Y, BT, x, bias, out, b0, nwg);
  }
}

// Round 5
// 579.605 us; speedup vs baseline: 1.2589x; 1.2589x over previous
//
#include <hip/hip_runtime.h>
#include <hip/hip_bf16.h>
#include <stdint.h>

// SpatioConvLayer: out = relu(x + b + einsum('iok,knm,bitm->botn', theta, Lk, x))
// (1) BT[n][k*1024+m] = bf16(Lk[k][n][m]); (2) Y[(b*48+t)*64+o][k*1024+m]
//     = sum_i theta[i,o,k] * x[b,i,t,m] (bf16, MFMA); (3) out = Y @ BT^T with
//     fused bias + residual + relu. Step (3) = 256x256x64, 4 phases/K-tile,
//     ONE raw s_barrier per phase (no mid-phase barrier, no sched_barrier
//     pinning), fragment reuse across phases, counted vmcnt once per tile.
//     T1 XCD swizzle + T2 LDS XOR swizzle + T5 setprio.

typedef short bs8 __attribute__((ext_vector_type(8)));   // 8 x bf16 fragment
typedef float f32x4 __attribute__((ext_vector_type(4))); // MFMA accumulator

#define NB   16
#define NC   64
#define NT   48
#define NN   1024
#define NKS  3
#define KDIM 3072  // NKS * NN
#define KT   48    // KDIM / 64 K-tiles

// f32 -> bf16 round-to-nearest-even (finite inputs only)
__device__ __forceinline__ short f2bs(float f) {
  uint32_t u = __builtin_bit_cast(uint32_t, f);
  u = (u + 0x7FFFu + ((u >> 16) & 1u)) >> 16;
  return (short)u;
}

__device__ __forceinline__ void gload16(const void* g, void* l) {
  __builtin_amdgcn_global_load_lds(
      (const __attribute__((address_space(1))) void*)g,
      (__attribute__((address_space(3))) void*)l, 16, 0, 0);
}

// ---------------- prep: BT[n][k*NN+m] = bf16(Lk[k][n][m]) -------------------
__global__ __launch_bounds__(256) void k_prep_bt(const float* __restrict__ Lk,
                                                 short* __restrict__ BT) {
  int gid = blockIdx.x * 256 + threadIdx.x;
  int e = gid * 4;
  int k = e >> 20;
  int rem = e & 1048575;
  int n = rem >> 10;
  int m = rem & 1023;
  float4 v = *reinterpret_cast<const float4*>(Lk + e);
  union { short s[4]; uint64_t u; } p;
  p.s[0] = f2bs(v.x); p.s[1] = f2bs(v.y); p.s[2] = f2bs(v.z); p.s[3] = f2bs(v.w);
  *reinterpret_cast<uint64_t*>(BT + (size_t)n * KDIM + k * NN + m) = p.u;
}

// ---------------- step1: Y[btl*64+o][k*NN+m] = sum_i th[i,o,k] x[b,i,t,m] ---
__global__ __launch_bounds__(256) void k_step1(const float* __restrict__ x,
                                               const float* __restrict__ theta,
                                               short* __restrict__ Y, int b0) {
  __shared__ __align__(16) short th[NKS * 64 * 72];  // [k][o][i] padded 64->72
  int tid = threadIdx.x;
  for (int idx = tid; idx < NC * NC * NKS; idx += 256) {
    int i = idx / (NC * NKS);
    int r = idx - i * (NC * NKS);
    int o = r / NKS;
    int k = r - o * NKS;
    th[(k * 64 + o) * 72 + i] = f2bs(theta[idx]);  // theta[i][o][k]
  }
  __syncthreads();

  int bid = blockIdx.x;
  int mt  = bid & 3;
  int btl = bid >> 2;
  int b_l = btl / NT;
  int t   = btl - b_l * NT;
  int b   = b0 + b_l;

  int lane = tid & 63, wave = tid >> 6;
  int l15 = lane & 15, lg = lane >> 4;
  const float* xb = x + (size_t)b * (NC * NT * NN) + (size_t)t * NN;
  int m0 = mt * 256 + wave * 64;
  size_t yrow0 = (size_t)btl * 64;

  for (int ni = 0; ni < 4; ++ni) {
    int mcol = m0 + ni * 16 + l15;
    float xv[16];
#pragma unroll
    for (int j = 0; j < 16; ++j) {
      int i = ((j >> 3) << 5) + lg * 8 + (j & 7);
      xv[j] = xb[(size_t)i * (NT * NN) + mcol];
    }
    f32x4 acc[3][4];
#pragma unroll
    for (int k = 0; k < 3; ++k)
#pragma unroll
      for (int mi = 0; mi < 4; ++mi)
        acc[k][mi] = (f32x4){0.f, 0.f, 0.f, 0.f};

#pragma unroll
    for (int ks = 0; ks < 2; ++ks) {
      bs8 bfrag;
#pragma unroll
      for (int j = 0; j < 8; ++j) bfrag[j] = f2bs(xv[ks * 8 + j]);
#pragma unroll
      for (int mi = 0; mi < 4; ++mi) {
#pragma unroll
        for (int k = 0; k < 3; ++k) {
          const bs8* ap = reinterpret_cast<const bs8*>(
              &th[(k * 64 + mi * 16 + l15) * 72 + ks * 32 + lg * 8]);
          acc[k][mi] = __builtin_amdgcn_mfma_f32_16x16x32_bf16(
              *ap, bfrag, acc[k][mi], 0, 0, 0);
        }
      }
    }
#pragma unroll
    for (int k = 0; k < 3; ++k)
#pragma unroll
      for (int mi = 0; mi < 4; ++mi)
#pragma unroll
        for (int q = 0; q < 4; ++q) {
          int o = mi * 16 + lg * 4 + q;
          Y[(yrow0 + o) * KDIM + k * NN + mcol] = f2bs(acc[k][mi][q]);
        }
  }
}

// ---------------- big GEMM: C = Y @ BT^T, 256^2, 1 barrier/phase ------------
// Phase order (0,0)->(0,1)->(1,1)->(1,0); frag reuse: A read at P0/P2 (8),
// B0 at P0 (4, held to P3), B1 at P1 (4, reused P2). 24 ds_read/tile/wave.
// Stage schedule: P0: A1(t+1)->buf^1; P1: B1(t+1)->buf^1; P2: A0(t+2)->buf;
// P3: B0(t+2)->buf. Slot-overwrite gaps (phase-end barriers between last
// read and stage): A0 read P0 / staged P2 (2); B0 read P0 / staged P3 (3);
// A1 read P2 / staged P0' (2); B1 read P1 / staged P1' (4). All >=2. Every
// phase's ds_reads are consumed by its COMPUTE (compiler lgkm waits) before
// that phase's end barrier => no read outlives a barrier.
// vmcnt(4) once per tile at P3 (in-flight 12 -> 4): completes exactly
// {A0,B0,A1,B1}(t+1); leaves {A0,B0}(t+2). Tail: tile KT-2 vmcnt(0).

__device__ __forceinline__ void stage_half(const short* __restrict__ src,
                                           short* lds, int h, int tid) {
  int wave = tid >> 6;
#pragma unroll
  for (int r = 0; r < 2; ++r) {
    int idx = h * 1024 + r * 512 + tid;
    int row = idx >> 3, c8 = idx & 7;
    int c8s = c8 ^ (row & 7);                     // inverse-swizzled source
    gload16(src + (size_t)row * KDIM + c8s * 8,
            lds + (h * 1024 + r * 512 + wave * 64) * 8);  // wave-uniform base
  }
}

#define VMC(N) asm volatile("s_waitcnt vmcnt(" #N ")" ::: "memory")
#define BARR() __builtin_amdgcn_s_barrier();

#define READ_A(DST, QM, P)                                                \
  _Pragma("unroll") for (int e = 0; e < 4; ++e)                           \
    _Pragma("unroll") for (int ks = 0; ks < 2; ++ks) {                    \
      int rw = (8 * (QM) + 2 * e + wr) * 16 + l15;                        \
      DST[e][ks] = *(const bs8*)&AL[(P) * 16384 + rw * 64 +               \
                    ((ks * 32 + lg * 8) ^ ((rw & 7) << 3))];              \
    }

#define READ_B(DST, QN, P)                                                \
  _Pragma("unroll") for (int f = 0; f < 2; ++f)                           \
    _Pragma("unroll") for (int ks = 0; ks < 2; ++ks) {                    \
      int rw = (8 * (QN) + 4 * f + wc) * 16 + l15;                        \
      DST[f][ks] = *(const bs8*)&BL[(P) * 16384 + rw * 64 +               \
                    ((ks * 32 + lg * 8) ^ ((rw & 7) << 3))];              \
    }

// ks-outer: dependent MFMAs on the same acc are 8 apart
#define COMPUTE(QM, AF, BF, QN)                                             \
  __builtin_amdgcn_s_setprio(1);                                            \
  _Pragma("unroll") for (int ks = 0; ks < 2; ++ks)                          \
    _Pragma("unroll") for (int e = 0; e < 4; ++e)                           \
      _Pragma("unroll") for (int f = 0; f < 2; ++f)                         \
        acc[4 * (QM) + e][2 * (QN) + f] =                                   \
            __builtin_amdgcn_mfma_f32_16x16x32_bf16(                        \
                AF[e][ks], BF[f][ks], acc[4 * (QM) + e][2 * (QN) + f],      \
                0, 0, 0);                                                   \
  __builtin_amdgcn_s_setprio(0);

// S1: t+1 exists (stage A1/B1); S2: t+2 exists (stage A0/B0); VM: tile vmcnt.
#define TILE(t, P, S1, S2, VM)                                              \
  {                                                                         \
    bs8 af[4][2], bf0[2][2], bf1[2][2];                                     \
    READ_A(af, 0, P);                                                       \
    READ_B(bf0, 0, P);                                                      \
    if (S1) stage_half(Yb + ((t) + 1) * 64, AL + ((P) ^ 1) * 16384, 1, tid);\
    COMPUTE(0, af, bf0, 0);                                                 \
    BARR();                                                                 \
    READ_B(bf1, 1, P);                                                      \
    if (S1) stage_half(BTb + ((t) + 1) * 64, BL + ((P) ^ 1) * 16384, 1, tid);\
    COMPUTE(0, af, bf1, 1);                                                 \
    BARR();                                                                 \
    READ_A(af, 1, P);                                                       \
    if (S2) stage_half(Yb + ((t) + 2) * 64, AL + (P) * 16384, 0, tid);      \
    COMPUTE(1, af, bf1, 1);                                                 \
    BARR();                                                                 \
    if (S2) stage_half(BTb + ((t) + 2) * 64, BL + (P) * 16384, 0, tid);     \
    COMPUTE(1, af, bf0, 0);                                                 \
    VM;                                                                     \
    BARR();                                                                 \
  }

__global__ __launch_bounds__(512, 2) void k_gemm(const short* __restrict__ Y,
                                                 const short* __restrict__ BT,
                                                 const float* __restrict__ x,
                                                 const float* __restrict__ bias,
                                                 float* __restrict__ out,
                                                 int b0, int nwg) {
  __shared__ __align__(16) short AL[2 * 16384];  // [buf][256][64] 64 KiB
  __shared__ __align__(16) short BL[2 * 16384];  // [buf][256][64] 64 KiB

  int bid = blockIdx.x;
  int cpx = nwg >> 3;                        // nwg % 8 == 0 -> bijective
  int swz = (bid & 7) * cpx + (bid >> 3);    // XCD-aware swizzle
  int colb = swz & 3;                        // 4 col-blocks (N=1024/256)
  int rowb = swz >> 2;

  int tid = threadIdx.x;
  int lane = tid & 63, wave = tid >> 6;
  int wr = wave >> 2, wc = wave & 3;         // 2M x 4N waves
  int l15 = lane & 15, lg = lane >> 4;
  int row0 = rowb * 256, col0 = colb * 256;

  const short* Yb  = Y  + (size_t)row0 * KDIM;
  const short* BTb = BT + (size_t)col0 * KDIM;

  f32x4 acc[8][4];
#pragma unroll
  for (int j = 0; j < 8; ++j)
#pragma unroll
    for (int i = 0; i < 4; ++i) acc[j][i] = (f32x4){0.f, 0.f, 0.f, 0.f};

  // prologue: tile0 (A0,A1,B0,B1) -> buf0; A0(1),B0(1) -> buf1 (12 loads)
  stage_half(Yb,        AL,         0, tid);
  stage_half(Yb,        AL,         1, tid);
  stage_half(BTb,       BL,         0, tid);
  stage_half(BTb,       BL,         1, tid);
  stage_half(Yb + 64,   AL + 16384, 0, tid);
  stage_half(BTb + 64,  BL + 16384, 0, tid);
  VMC(4);                                    // tile0 landed; {A0,B0}(1) fly
  BARR();

  for (int t = 0; t < KT - 2; t += 2) {
    TILE(t,     0, 1, 1, VMC(4));
    TILE(t + 1, 1, 1, 1, VMC(4));
  }
  TILE(KT - 2, 0, 1, 0, VMC(0));
  TILE(KT - 1, 1, 0, 0, (void)0);

  // epilogue: out = relu(acc + bias[o] + x); abs M-frag 2j+wr, N-frag 4i+wc
#pragma unroll
  for (int j = 0; j < 8; ++j) {
#pragma unroll
    for (int q = 0; q < 4; ++q) {
      int r = row0 + (2 * j + wr) * 16 + lg * 4 + q;  // chunk-local row
      int o = r & 63;
      int btl = r >> 6;
      int tt = btl % NT;
      int bb = b0 + btl / NT;
      float bo = bias[o];
      size_t obase = ((size_t)(bb * 64 + o) * NT + tt) * NN;
#pragma unroll
      for (int i = 0; i < 4; ++i) {
        int n = col0 + (4 * i + wc) * 16 + l15;
        size_t oidx = obase + n;
        float v = acc[j][i][q] + bo + x[oidx];
        out[oidx] = v > 0.f ? v : 0.f;
      }
    }
  }
}

extern "C" void kernel_launch(void* const* d_in, const int* in_sizes, int n_in,
                              void* d_out, int out_size, void* d_ws, size_t ws_size,
                              hipStream_t stream) {
  const float* x     = (const float*)d_in[0];
  const float* Lk    = (const float*)d_in[1];
  const float* theta = (const float*)d_in[2];
  const float* bias  = (const float*)d_in[3];
  float* out = (float*)d_out;

  char* ws = (char*)d_ws;
  short* BT = (short*)ws;                         // 6.29 MB
  short* Y  = (short*)(ws + (size_t)(8u << 20));  // up to 302 MB
  size_t avail = ws_size > ((size_t)8u << 20) ? ws_size - ((size_t)8u << 20) : 0;
  size_t perB = (size_t)NT * NC * KDIM * 2;       // 18,874,368 B per batch-row
  int bc = 16;
  while (bc > 1 && (size_t)bc * perB > avail) bc >>= 1;  // chunk over b if needed

  k_prep_bt<<<dim3(3072), dim3(256), 0, stream>>>(Lk, BT);
  for (int b0 = 0; b0 < NB; b0 += bc) {
    k_step1<<<dim3(bc * 192), dim3(256), 0, stream>>>(x, theta, Y, b0);
    int nwg = bc * 48;  // (bc*3072/256 rowb) * 4 colb, divisible by 8
    k_gemm<<<dim3(nwg), dim3(512), 0, stream>>>(Y, BT, x, bias, out, b0, nwg);
  }
}

// Round 6
// 543.740 us; speedup vs baseline: 1.3420x; 1.0660x over previous
//
#include <hip/hip_runtime.h>
#include <hip/hip_bf16.h>
#include <stdint.h>

// SpatioConvLayer: out = relu(x + b + einsum('iok,knm,bitm->botn', theta, Lk, x))
// (1) BT[n][k*1024+m] = bf16(Lk[k][n][m]); (2) Y[(b*48+t)*64+o][k*1024+m]
//     = sum_i theta[i,o,k] * x[b,i,t,m] (bf16, MFMA, LDS-staged x); (3) out =
//     Y @ BT^T fused bias+residual+relu. R6: k_gemm = 128x128xBK64, 4 waves,
//     double-buffered 64KB LDS -> 2 blocks/CU (TLP covers stalls; m97 thesis),
//     XOR swizzle + gload_lds w16 + setprio + ks-outer MFMA + XCD swizzle.

typedef short bs8 __attribute__((ext_vector_type(8)));   // 8 x bf16 fragment
typedef float f32x4 __attribute__((ext_vector_type(4))); // MFMA accumulator

#define NB   16
#define NC   64
#define NT   48
#define NN   1024
#define NKS  3
#define KDIM 3072  // NKS * NN
#define KT   48    // KDIM / 64 K-tiles

// f32 -> bf16 round-to-nearest-even (finite inputs only)
__device__ __forceinline__ short f2bs(float f) {
  uint32_t u = __builtin_bit_cast(uint32_t, f);
  u = (u + 0x7FFFu + ((u >> 16) & 1u)) >> 16;
  return (short)u;
}

__device__ __forceinline__ void gload16(const void* g, void* l) {
  __builtin_amdgcn_global_load_lds(
      (const __attribute__((address_space(1))) void*)g,
      (__attribute__((address_space(3))) void*)l, 16, 0, 0);
}

// ---------------- prep: BT[n][k*NN+m] = bf16(Lk[k][n][m]) -------------------
__global__ __launch_bounds__(256) void k_prep_bt(const float* __restrict__ Lk,
                                                 short* __restrict__ BT) {
  int gid = blockIdx.x * 256 + threadIdx.x;
  int e = gid * 4;
  int k = e >> 20;
  int rem = e & 1048575;
  int n = rem >> 10;
  int m = rem & 1023;
  float4 v = *reinterpret_cast<const float4*>(Lk + e);
  union { short s[4]; uint64_t u; } p;
  p.s[0] = f2bs(v.x); p.s[1] = f2bs(v.y); p.s[2] = f2bs(v.z); p.s[3] = f2bs(v.w);
  *reinterpret_cast<uint64_t*>(BT + (size_t)n * KDIM + k * NN + m) = p.u;
}

// ---------------- step1: Y[btl*64+o][k*NN+m] = sum_i th[i,o,k] x[b,i,t,m] ---
// grid: bc*48*8 blocks (8 m-tiles of 128), 256 threads. x-slice [64 i][128 m]
// f32 staged into LDS via coalesced gload_lds (8x16B/thread), then per-lane
// scalar LDS reads build the MFMA B-fragment (i is lane-private -> no xpose).
__global__ __launch_bounds__(256, 2) void k_step1(const float* __restrict__ x,
                                                  const float* __restrict__ theta,
                                                  short* __restrict__ Y, int b0) {
  __shared__ __align__(16) short th[NKS * 64 * 72];  // [k][o][i] padded, 27.6KB
  __shared__ __align__(16) float xs[64 * 128];       // [i][m] slice, 32KB
  int tid = threadIdx.x;
  int wave = tid >> 6;
  for (int idx = tid; idx < NC * NC * NKS; idx += 256) {
    int i = idx / (NC * NKS);
    int r = idx - i * (NC * NKS);
    int o = r / NKS;
    int k = r - o * NKS;
    th[(k * 64 + o) * 72 + i] = f2bs(theta[idx]);  // theta[i][o][k]
  }

  int bid = blockIdx.x;
  int mt  = bid & 7;            // m-tile of 128
  int btl = bid >> 3;
  int b_l = btl / NT;
  int t   = btl - b_l * NT;
  int b   = b0 + b_l;
  const float* xb = x + (size_t)b * (NC * NT * NN) + (size_t)t * NN + mt * 128;

  // stage x-slice: row = i (0..63), 32 chunks of 16B per row, linear dest
#pragma unroll
  for (int c = 0; c < 8; ++c) {
    int idx = c * 256 + tid;
    int row = idx >> 5, ch = idx & 31;
    gload16(xb + (size_t)row * (NT * NN) + ch * 4,
            xs + (c * 256 + wave * 64) * 4);  // wave-uniform base, 16B/lane
  }
  __syncthreads();  // drains vmcnt (xs) + lgkm (th)

  int lane = tid & 63;
  int l15 = lane & 15, lg = lane >> 4;
  size_t yrow0 = (size_t)btl * 64;

  for (int nni = 0; nni < 2; ++nni) {
    int mloc = wave * 32 + nni * 16 + l15;
    float xv[16];
#pragma unroll
    for (int j = 0; j < 16; ++j) {
      int i = ((j >> 3) << 5) + lg * 8 + (j & 7);
      xv[j] = xs[i * 128 + mloc];
    }
    f32x4 acc[3][4];
#pragma unroll
    for (int k = 0; k < 3; ++k)
#pragma unroll
      for (int mi = 0; mi < 4; ++mi)
        acc[k][mi] = (f32x4){0.f, 0.f, 0.f, 0.f};

#pragma unroll
    for (int ks = 0; ks < 2; ++ks) {
      bs8 bfrag;
#pragma unroll
      for (int j = 0; j < 8; ++j) bfrag[j] = f2bs(xv[ks * 8 + j]);
#pragma unroll
      for (int mi = 0; mi < 4; ++mi) {
#pragma unroll
        for (int k = 0; k < 3; ++k) {
          const bs8* ap = reinterpret_cast<const bs8*>(
              &th[(k * 64 + mi * 16 + l15) * 72 + ks * 32 + lg * 8]);
          acc[k][mi] = __builtin_amdgcn_mfma_f32_16x16x32_bf16(
              *ap, bfrag, acc[k][mi], 0, 0, 0);
        }
      }
    }
    int mcol = mt * 128 + mloc;
#pragma unroll
    for (int k = 0; k < 3; ++k)
#pragma unroll
      for (int mi = 0; mi < 4; ++mi)
#pragma unroll
        for (int q = 0; q < 4; ++q) {
          int o = mi * 16 + lg * 4 + q;
          Y[(yrow0 + o) * KDIM + k * NN + mcol] = f2bs(acc[k][mi][q]);
        }
  }
}

// ---------------- big GEMM: C = Y @ BT^T, 128^2 dbuf, 2 blocks/CU -----------
// 4 waves (2x2), per-wave 64x64 out (acc 64 f32). Per tile: stage t+1 into
// buf p^1 (8 gload16, issued FIRST), read frags from buf p (16 ds_read_b128),
// 32 MFMA (ks-outer), vmcnt(0), one s_barrier. Cross-wave safety: a wave's
// ds_reads complete before its MFMAs (compiler lgkm), which precede its
// barrier; stages into p happen only after the barrier => no WAR race.
// TLP: 64KB LDS + <=256 unified VGPR -> 2 independent blocks/CU cover the
// vmcnt drain and read latency (m97/m114 mechanism).
// T2 swizzle: byte ^= (row&7)<<4 via inverse-permuted global source chunk.

__device__ __forceinline__ void stage_tile(const short* __restrict__ src,
                                           short* lds, int tid) {
  int wave = tid >> 6;
#pragma unroll
  for (int c = 0; c < 4; ++c) {
    int idx = c * 256 + tid;
    int row = idx >> 3, c8 = idx & 7;
    int c8s = c8 ^ (row & 7);                     // inverse-swizzled source
    gload16(src + (size_t)row * KDIM + c8s * 8,
            lds + (c * 256 + wave * 64) * 8);     // wave-uniform base
  }
}

#define VMC(N) asm volatile("s_waitcnt vmcnt(" #N ")" ::: "memory")
#define BARR() __builtin_amdgcn_s_barrier();

#define READ_AB(P)                                                        \
  _Pragma("unroll") for (int j = 0; j < 4; ++j)                           \
    _Pragma("unroll") for (int ks = 0; ks < 2; ++ks) {                    \
      int rw = (2 * j + wr) * 16 + l15;                                   \
      af[j][ks] = *(const bs8*)&AL[(P) * 8192 + rw * 64 +                 \
                    ((ks * 32 + lg * 8) ^ ((rw & 7) << 3))];              \
      int rwb = (2 * j + wc) * 16 + l15;                                  \
      bf[j][ks] = *(const bs8*)&BL[(P) * 8192 + rwb * 64 +                \
                    ((ks * 32 + lg * 8) ^ ((rwb & 7) << 3))];             \
    }

#define COMPUTE()                                                           \
  __builtin_amdgcn_s_setprio(1);                                            \
  _Pragma("unroll") for (int ks = 0; ks < 2; ++ks)                          \
    _Pragma("unroll") for (int j = 0; j < 4; ++j)                           \
      _Pragma("unroll") for (int i = 0; i < 4; ++i)                         \
        acc[j][i] = __builtin_amdgcn_mfma_f32_16x16x32_bf16(                \
            af[j][ks], bf[i][ks], acc[j][i], 0, 0, 0);                      \
  __builtin_amdgcn_s_setprio(0);

#define TILE(t, P, S)                                                       \
  {                                                                         \
    bs8 af[4][2], bf[4][2];                                                 \
    if (S) {                                                                \
      stage_tile(Yb + ((t) + 1) * 64, AL + ((P) ^ 1) * 8192, tid);          \
      stage_tile(BTb + ((t) + 1) * 64, BL + ((P) ^ 1) * 8192, tid);         \
    }                                                                       \
    READ_AB(P);                                                             \
    COMPUTE();                                                              \
    if (S) {                                                                \
      VMC(0);                                                               \
      BARR();                                                               \
    }                                                                       \
  }

__global__ __launch_bounds__(256, 2) void k_gemm(const short* __restrict__ Y,
                                                 const short* __restrict__ BT,
                                                 const float* __restrict__ x,
                                                 const float* __restrict__ bias,
                                                 float* __restrict__ out,
                                                 int b0, int nwg) {
  __shared__ __align__(16) short AL[2 * 8192];  // [buf][128][64] 32 KiB
  __shared__ __align__(16) short BL[2 * 8192];  // [buf][128][64] 32 KiB

  int bid = blockIdx.x;
  int cpx = nwg >> 3;                        // nwg % 8 == 0 -> bijective
  int swz = (bid & 7) * cpx + (bid >> 3);    // XCD-aware swizzle
  int colb = swz & 7;                        // 8 col-blocks (N=1024/128)
  int rowb = swz >> 3;

  int tid = threadIdx.x;
  int lane = tid & 63, wave = tid >> 6;
  int wr = wave >> 1, wc = wave & 1;         // 2M x 2N waves
  int l15 = lane & 15, lg = lane >> 4;
  int row0 = rowb * 128, col0 = colb * 128;

  const short* Yb  = Y  + (size_t)row0 * KDIM;
  const short* BTb = BT + (size_t)col0 * KDIM;

  f32x4 acc[4][4];
#pragma unroll
  for (int j = 0; j < 4; ++j)
#pragma unroll
    for (int i = 0; i < 4; ++i) acc[j][i] = (f32x4){0.f, 0.f, 0.f, 0.f};

  // prologue: tile0 -> buf0
  stage_tile(Yb,  AL, tid);
  stage_tile(BTb, BL, tid);
  VMC(0);
  BARR();

  for (int t = 0; t < KT - 2; t += 2) {
    TILE(t,     0, 1);
    TILE(t + 1, 1, 1);
  }
  TILE(KT - 2, 0, 1);
  TILE(KT - 1, 1, 0);

  // epilogue: out = relu(acc + bias[o] + x); M-frag 2j+wr, N-frag 2i+wc
#pragma unroll
  for (int j = 0; j < 4; ++j) {
#pragma unroll
    for (int q = 0; q < 4; ++q) {
      int r = row0 + (2 * j + wr) * 16 + lg * 4 + q;  // chunk-local row
      int o = r & 63;
      int btl = r >> 6;
      int tt = btl % NT;
      int bb = b0 + btl / NT;
      float bo = bias[o];
      size_t obase = ((size_t)(bb * 64 + o) * NT + tt) * NN;
#pragma unroll
      for (int i = 0; i < 4; ++i) {
        int n = col0 + (2 * i + wc) * 16 + l15;
        size_t oidx = obase + n;
        float v = acc[j][i][q] + bo + x[oidx];
        out[oidx] = v > 0.f ? v : 0.f;
      }
    }
  }
}

extern "C" void kernel_launch(void* const* d_in, const int* in_sizes, int n_in,
                              void* d_out, int out_size, void* d_ws, size_t ws_size,
                              hipStream_t stream) {
  const float* x     = (const float*)d_in[0];
  const float* Lk    = (const float*)d_in[1];
  const float* theta = (const float*)d_in[2];
  const float* bias  = (const float*)d_in[3];
  float* out = (float*)d_out;

  char* ws = (char*)d_ws;
  short* BT = (short*)ws;                         // 6.29 MB
  short* Y  = (short*)(ws + (size_t)(8u << 20));  // up to 302 MB
  size_t avail = ws_size > ((size_t)8u << 20) ? ws_size - ((size_t)8u << 20) : 0;
  size_t perB = (size_t)NT * NC * KDIM * 2;       // 18,874,368 B per batch-row
  int bc = 16;
  while (bc > 1 && (size_t)bc * perB > avail) bc >>= 1;  // chunk over b if needed

  k_prep_bt<<<dim3(3072), dim3(256), 0, stream>>>(Lk, BT);
  for (int b0 = 0; b0 < NB; b0 += bc) {
    k_step1<<<dim3(bc * 384), dim3(256), 0, stream>>>(x, theta, Y, b0);
    int nwg = bc * 192;  // (bc*3072/128 rowb) * 8 colb, divisible by 8
    k_gemm<<<dim3(nwg), dim3(256), 0, stream>>>(Y, BT, x, bias, out, b0, nwg);
  }
}

// Round 7
// 485.728 us; speedup vs baseline: 1.5022x; 1.1194x over previous
//
#include <hip/hip_runtime.h>
#include <hip/hip_bf16.h>
#include <stdint.h>

// SpatioConvLayer: out = relu(x + b + einsum('iok,knm,bitm->botn', theta, Lk, x))
// (1) BT[n][k*1024+m] = bf16(Lk[k][n][m]); (2) Y[(b*48+t)*64+o][k*1024+m]
//     = sum_i theta[i,o,k] * x[b,i,t,m] (bf16, MFMA, LDS-staged x); (3) out =
//     Y @ BT^T fused bias+residual+relu, 256x256x64, 4 phases/K-tile.
// R7: barrier BEFORE each COMPUTE (reads pre-barrier, unpinned) so the
//     compiler can interleave phase k+1's ds_reads into phase k's MFMA
//     cluster -- LDS service overlaps MFMA issue instead of serializing.

typedef short bs8 __attribute__((ext_vector_type(8)));   // 8 x bf16 fragment
typedef float f32x4 __attribute__((ext_vector_type(4))); // MFMA accumulator

#define NB   16
#define NC   64
#define NT   48
#define NN   1024
#define NKS  3
#define KDIM 3072  // NKS * NN
#define KT   48    // KDIM / 64 K-tiles

// f32 -> bf16 round-to-nearest-even (finite inputs only)
__device__ __forceinline__ short f2bs(float f) {
  uint32_t u = __builtin_bit_cast(uint32_t, f);
  u = (u + 0x7FFFu + ((u >> 16) & 1u)) >> 16;
  return (short)u;
}

__device__ __forceinline__ void gload16(const void* g, void* l) {
  __builtin_amdgcn_global_load_lds(
      (const __attribute__((address_space(1))) void*)g,
      (__attribute__((address_space(3))) void*)l, 16, 0, 0);
}

// ---------------- prep: BT[n][k*NN+m] = bf16(Lk[k][n][m]) -------------------
__global__ __launch_bounds__(256) void k_prep_bt(const float* __restrict__ Lk,
                                                 short* __restrict__ BT) {
  int gid = blockIdx.x * 256 + threadIdx.x;
  int e = gid * 4;
  int k = e >> 20;
  int rem = e & 1048575;
  int n = rem >> 10;
  int m = rem & 1023;
  float4 v = *reinterpret_cast<const float4*>(Lk + e);
  union { short s[4]; uint64_t u; } p;
  p.s[0] = f2bs(v.x); p.s[1] = f2bs(v.y); p.s[2] = f2bs(v.z); p.s[3] = f2bs(v.w);
  *reinterpret_cast<uint64_t*>(BT + (size_t)n * KDIM + k * NN + m) = p.u;
}

// ---------------- step1: Y[btl*64+o][k*NN+m] = sum_i th[i,o,k] x[b,i,t,m] ---
// grid: bc*48*8 blocks (8 m-tiles of 128), 256 threads. x-slice [64 i][128 m]
// f32 staged into LDS via coalesced gload_lds, then per-lane scalar LDS reads
// build the MFMA B-fragment (i is lane-private -> no transpose needed).
__global__ __launch_bounds__(256, 2) void k_step1(const float* __restrict__ x,
                                                  const float* __restrict__ theta,
                                                  short* __restrict__ Y, int b0) {
  __shared__ __align__(16) short th[NKS * 64 * 72];  // [k][o][i] padded, 27.6KB
  __shared__ __align__(16) float xs[64 * 128];       // [i][m] slice, 32KB
  int tid = threadIdx.x;
  int wave = tid >> 6;
  for (int idx = tid; idx < NC * NC * NKS; idx += 256) {
    int i = idx / (NC * NKS);
    int r = idx - i * (NC * NKS);
    int o = r / NKS;
    int k = r - o * NKS;
    th[(k * 64 + o) * 72 + i] = f2bs(theta[idx]);  // theta[i][o][k]
  }

  int bid = blockIdx.x;
  int mt  = bid & 7;            // m-tile of 128
  int btl = bid >> 3;
  int b_l = btl / NT;
  int t   = btl - b_l * NT;
  int b   = b0 + b_l;
  const float* xb = x + (size_t)b * (NC * NT * NN) + (size_t)t * NN + mt * 128;

  // stage x-slice: row = i (0..63), 32 chunks of 16B per row, linear dest
#pragma unroll
  for (int c = 0; c < 8; ++c) {
    int idx = c * 256 + tid;
    int row = idx >> 5, ch = idx & 31;
    gload16(xb + (size_t)row * (NT * NN) + ch * 4,
            xs + (c * 256 + wave * 64) * 4);  // wave-uniform base, 16B/lane
  }
  __syncthreads();  // drains vmcnt (xs) + lgkm (th)

  int lane = tid & 63;
  int l15 = lane & 15, lg = lane >> 4;
  size_t yrow0 = (size_t)btl * 64;

  for (int nni = 0; nni < 2; ++nni) {
    int mloc = wave * 32 + nni * 16 + l15;
    float xv[16];
#pragma unroll
    for (int j = 0; j < 16; ++j) {
      int i = ((j >> 3) << 5) + lg * 8 + (j & 7);
      xv[j] = xs[i * 128 + mloc];
    }
    f32x4 acc[3][4];
#pragma unroll
    for (int k = 0; k < 3; ++k)
#pragma unroll
      for (int mi = 0; mi < 4; ++mi)
        acc[k][mi] = (f32x4){0.f, 0.f, 0.f, 0.f};

#pragma unroll
    for (int ks = 0; ks < 2; ++ks) {
      bs8 bfrag;
#pragma unroll
      for (int j = 0; j < 8; ++j) bfrag[j] = f2bs(xv[ks * 8 + j]);
#pragma unroll
      for (int mi = 0; mi < 4; ++mi) {
#pragma unroll
        for (int k = 0; k < 3; ++k) {
          const bs8* ap = reinterpret_cast<const bs8*>(
              &th[(k * 64 + mi * 16 + l15) * 72 + ks * 32 + lg * 8]);
          acc[k][mi] = __builtin_amdgcn_mfma_f32_16x16x32_bf16(
              *ap, bfrag, acc[k][mi], 0, 0, 0);
        }
      }
    }
    int mcol = mt * 128 + mloc;
#pragma unroll
    for (int k = 0; k < 3; ++k)
#pragma unroll
      for (int mi = 0; mi < 4; ++mi)
#pragma unroll
        for (int q = 0; q < 4; ++q) {
          int o = mi * 16 + lg * 4 + q;
          Y[(yrow0 + o) * KDIM + k * NN + mcol] = f2bs(acc[k][mi][q]);
        }
  }
}

// ---------------- big GEMM: C = Y @ BT^T, 256^2, bar-before-compute ---------
// Phase order (0,0)->(0,1)->(1,1)->(1,0); frag reuse: A read at P0/P2 (8),
// B0 at P0 (held to P3), B1 at P1 (reused P2). 24 ds_read/tile/wave.
// Stream per tile: [R(P0);stageA1';bar][C(P0);R(P1);stageB1';bar][C(P1);
// R(P2);stageA0'';bar][C(P2);stageB0'';VMC(4);bar][C(P3); next tile R...].
// C(k) and R(k+1) are unseparated -> compiler interleaves next reads into
// the MFMA cluster; barrier wait absorbs residual LDS service.
// Stage-slot safety (>=1 barrier between a slot's last read and its
// overwrite): A0 read preP0-bar / staged preP2-bar (2 bars); B0 preP0/preP3
// (3); A1 preP2(t-1)/preP0(t) (2); B1 preP1(t-1)/preP1(t) (4). vmcnt(4) at
// P3 pre-barrier: completes {A0,B0,A1,B1}(t+1), leaves {A0,B0}(t+2); all
// waves pass it before the barrier releases -> t+1 reads are safe.

__device__ __forceinline__ void stage_half(const short* __restrict__ src,
                                           short* lds, int h, int tid) {
  int wave = tid >> 6;
#pragma unroll
  for (int r = 0; r < 2; ++r) {
    int idx = h * 1024 + r * 512 + tid;
    int row = idx >> 3, c8 = idx & 7;
    int c8s = c8 ^ (row & 7);                     // inverse-swizzled source
    gload16(src + (size_t)row * KDIM + c8s * 8,
            lds + (h * 1024 + r * 512 + wave * 64) * 8);  // wave-uniform base
  }
}

#define VMC(N) asm volatile("s_waitcnt vmcnt(" #N ")" ::: "memory")
#define BARR() __builtin_amdgcn_s_barrier();

#define READ_A(DST, QM, P)                                                \
  _Pragma("unroll") for (int e = 0; e < 4; ++e)                           \
    _Pragma("unroll") for (int ks = 0; ks < 2; ++ks) {                    \
      int rw = (8 * (QM) + 2 * e + wr) * 16 + l15;                        \
      DST[e][ks] = *(const bs8*)&AL[(P) * 16384 + rw * 64 +               \
                    ((ks * 32 + lg * 8) ^ ((rw & 7) << 3))];              \
    }

#define READ_B(DST, QN, P)                                                \
  _Pragma("unroll") for (int f = 0; f < 2; ++f)                           \
    _Pragma("unroll") for (int ks = 0; ks < 2; ++ks) {                    \
      int rw = (8 * (QN) + 4 * f + wc) * 16 + l15;                        \
      DST[f][ks] = *(const bs8*)&BL[(P) * 16384 + rw * 64 +               \
                    ((ks * 32 + lg * 8) ^ ((rw & 7) << 3))];              \
    }

// ks-outer: dependent MFMAs on the same acc are 8 apart
#define COMPUTE(QM, AF, BF, QN)                                             \
  __builtin_amdgcn_s_setprio(1);                                            \
  _Pragma("unroll") for (int ks = 0; ks < 2; ++ks)                          \
    _Pragma("unroll") for (int e = 0; e < 4; ++e)                           \
      _Pragma("unroll") for (int f = 0; f < 2; ++f)                         \
        acc[4 * (QM) + e][2 * (QN) + f] =                                   \
            __builtin_amdgcn_mfma_f32_16x16x32_bf16(                        \
                AF[e][ks], BF[f][ks], acc[4 * (QM) + e][2 * (QN) + f],      \
                0, 0, 0);                                                   \
  __builtin_amdgcn_s_setprio(0);

// S1: t+1 exists (stage A1/B1); S2: t+2 exists (stage A0/B0); VM: tile vmcnt.
#define TILE(t, P, S1, S2, VM)                                              \
  {                                                                         \
    bs8 af[4][2], bf0[2][2], bf1[2][2];                                     \
    READ_A(af, 0, P);                                                       \
    READ_B(bf0, 0, P);                                                      \
    if (S1) stage_half(Yb + ((t) + 1) * 64, AL + ((P) ^ 1) * 16384, 1, tid);\
    BARR();                                                                 \
    COMPUTE(0, af, bf0, 0);                                                 \
    READ_B(bf1, 1, P);                                                      \
    if (S1) stage_half(BTb + ((t) + 1) * 64, BL + ((P) ^ 1) * 16384, 1, tid);\
    BARR();                                                                 \
    COMPUTE(0, af, bf1, 1);                                                 \
    READ_A(af, 1, P);                                                       \
    if (S2) stage_half(Yb + ((t) + 2) * 64, AL + (P) * 16384, 0, tid);      \
    BARR();                                                                 \
    COMPUTE(1, af, bf1, 1);                                                 \
    if (S2) stage_half(BTb + ((t) + 2) * 64, BL + (P) * 16384, 0, tid);     \
    VM;                                                                     \
    BARR();                                                                 \
    COMPUTE(1, af, bf0, 0);                                                 \
  }

__global__ __launch_bounds__(512, 2) void k_gemm(const short* __restrict__ Y,
                                                 const short* __restrict__ BT,
                                                 const float* __restrict__ x,
                                                 const float* __restrict__ bias,
                                                 float* __restrict__ out,
                                                 int b0, int nwg) {
  __shared__ __align__(16) short AL[2 * 16384];  // [buf][256][64] 64 KiB
  __shared__ __align__(16) short BL[2 * 16384];  // [buf][256][64] 64 KiB

  int bid = blockIdx.x;
  int cpx = nwg >> 3;                        // nwg % 8 == 0 -> bijective
  int swz = (bid & 7) * cpx + (bid >> 3);    // XCD-aware swizzle
  int colb = swz & 3;                        // 4 col-blocks (N=1024/256)
  int rowb = swz >> 2;

  int tid = threadIdx.x;
  int lane = tid & 63, wave = tid >> 6;
  int wr = wave >> 2, wc = wave & 3;         // 2M x 4N waves
  int l15 = lane & 15, lg = lane >> 4;
  int row0 = rowb * 256, col0 = colb * 256;

  const short* Yb  = Y  + (size_t)row0 * KDIM;
  const short* BTb = BT + (size_t)col0 * KDIM;

  f32x4 acc[8][4];
#pragma unroll
  for (int j = 0; j < 8; ++j)
#pragma unroll
    for (int i = 0; i < 4; ++i) acc[j][i] = (f32x4){0.f, 0.f, 0.f, 0.f};

  // prologue: tile0 (A0,A1,B0,B1) -> buf0; A0(1),B0(1) -> buf1 (12 loads)
  stage_half(Yb,        AL,         0, tid);
  stage_half(Yb,        AL,         1, tid);
  stage_half(BTb,       BL,         0, tid);
  stage_half(BTb,       BL,         1, tid);
  stage_half(Yb + 64,   AL + 16384, 0, tid);
  stage_half(BTb + 64,  BL + 16384, 0, tid);
  VMC(4);                                    // tile0 landed; {A0,B0}(1) fly
  BARR();

  for (int t = 0; t < KT - 2; t += 2) {
    TILE(t,     0, 1, 1, VMC(4));
    TILE(t + 1, 1, 1, 1, VMC(4));
  }
  TILE(KT - 2, 0, 1, 0, VMC(0));
  TILE(KT - 1, 1, 0, 0, (void)0);

  // epilogue: out = relu(acc + bias[o] + x); abs M-frag 2j+wr, N-frag 4i+wc
#pragma unroll
  for (int j = 0; j < 8; ++j) {
#pragma unroll
    for (int q = 0; q < 4; ++q) {
      int r = row0 + (2 * j + wr) * 16 + lg * 4 + q;  // chunk-local row
      int o = r & 63;
      int btl = r >> 6;
      int tt = btl % NT;
      int bb = b0 + btl / NT;
      float bo = bias[o];
      size_t obase = ((size_t)(bb * 64 + o) * NT + tt) * NN;
#pragma unroll
      for (int i = 0; i < 4; ++i) {
        int n = col0 + (4 * i + wc) * 16 + l15;
        size_t oidx = obase + n;
        float v = acc[j][i][q] + bo + x[oidx];
        out[oidx] = v > 0.f ? v : 0.f;
      }
    }
  }
}

extern "C" void kernel_launch(void* const* d_in, const int* in_sizes, int n_in,
                              void* d_out, int out_size, void* d_ws, size_t ws_size,
                              hipStream_t stream) {
  const float* x     = (const float*)d_in[0];
  const float* Lk    = (const float*)d_in[1];
  const float* theta = (const float*)d_in[2];
  const float* bias  = (const float*)d_in[3];
  float* out = (float*)d_out;

  char* ws = (char*)d_ws;
  short* BT = (short*)ws;                         // 6.29 MB
  short* Y  = (short*)(ws + (size_t)(8u << 20));  // up to 302 MB
  size_t avail = ws_size > ((size_t)8u << 20) ? ws_size - ((size_t)8u << 20) : 0;
  size_t perB = (size_t)NT * NC * KDIM * 2;       // 18,874,368 B per batch-row
  int bc = 16;
  while (bc > 1 && (size_t)bc * perB > avail) bc >>= 1;  // chunk over b if needed

  k_prep_bt<<<dim3(3072), dim3(256), 0, stream>>>(Lk, BT);
  for (int b0 = 0; b0 < NB; b0 += bc) {
    k_step1<<<dim3(bc * 384), dim3(256), 0, stream>>>(x, theta, Y, b0);
    int nwg = bc * 48;  // (bc*3072/256 rowb) * 4 colb, divisible by 8
    k_gemm<<<dim3(nwg), dim3(512), 0, stream>>>(Y, BT, x, bias, out, b0, nwg);
  }
}